// Round 1
// baseline (386.335 us; speedup 1.0000x reference)
//
#include <hip/hip_runtime.h>
#include <hip/hip_bf16.h>

typedef __bf16 bf16;
typedef __attribute__((ext_vector_type(8))) __bf16 bf16x8;
typedef __attribute__((ext_vector_type(4))) __bf16 bf16x4;
typedef __attribute__((ext_vector_type(4))) float f32x4;

#define D_MODEL 1024
#define NHEAD 16
#define DK 64
#define BB 4
#define SS 2048
#define MM 8192
#define KK 2048
#define NN 3072

#define LDP 72
#define QSCALE 0.18033688011112042f  // 0.125 * log2(e)

__device__ __forceinline__ void glds16(const bf16* g, bf16* s) {
    __builtin_amdgcn_global_load_lds(
        (const __attribute__((address_space(1))) void*)g,
        (__attribute__((address_space(3))) void*)s, 16, 0, 0);
}

// ---------------------------------------------------------------------------
// Tile-packed XOR-swizzled layout: tile=128 rows x 64 cols, chunk c of row mi
// at slot mi*8 + (c^(mi&7)); tiles [row_tile][k_tile].  (unchanged)
// ---------------------------------------------------------------------------
__device__ __forceinline__ void pack_chunk(const float* __restrict__ src,
                                           bf16* __restrict__ dst,
                                           int row_off, int col_off, int idx) {
    int m = idx >> 7;        // source row (1024 cols = 128 chunks)
    int cl = idx & 127;
    const float4* s4 = (const float4*)&src[((size_t)m << 10) + cl * 8];
    float4 v0 = s4[0], v1 = s4[1];
    bf16x8 o;
    o[0]=(bf16)v0.x; o[1]=(bf16)v0.y; o[2]=(bf16)v0.z; o[3]=(bf16)v0.w;
    o[4]=(bf16)v1.x; o[5]=(bf16)v1.y; o[6]=(bf16)v1.z; o[7]=(bf16)v1.w;
    int r = row_off + m;
    int k = col_off + cl * 8;
    int mi = r & 127, mt = r >> 7;
    int c = (k >> 3) & 7, kt = k >> 6;
    int slot = mi * 8 + (c ^ (mi & 7));
    *(bf16x8*)&dst[(((((size_t)mt * 32 + kt) << 10) + slot) << 3)] = o;
}

// One kernel packs X (2*2^20 chunks), W (6*2^17 chunks), bias (tail block).
__global__ void pack_all(const float* __restrict__ Xs, const float* __restrict__ Xt,
                         const float* __restrict__ Wqs, const float* __restrict__ Wqt,
                         const float* __restrict__ Wks, const float* __restrict__ Wkt,
                         const float* __restrict__ Wvs, const float* __restrict__ Wvt,
                         const float* __restrict__ bqs, const float* __restrict__ bqt,
                         const float* __restrict__ bks, const float* __restrict__ bkt,
                         const float* __restrict__ bvs, const float* __restrict__ bvt,
                         bf16* __restrict__ Xp, bf16* __restrict__ Wp,
                         float* __restrict__ biasc) {
    int blk = blockIdx.x;
    if (blk < 8192) {                      // X: 2 * 1,048,576 chunks
        int i = blk * 256 + threadIdx.x;
        int sel = i >> 20;
        int idx = i & 1048575;
        pack_chunk(sel ? Xt : Xs, Xp, 0, sel ? 1024 : 0, idx);
        return;
    }
    if (blk < 11264) {                     // W: 6 * 131,072 chunks
        int i = (blk - 8192) * 256 + threadIdx.x;
        int gi = i >> 17;
        int idx = i & 131071;
        const float* src = (gi == 0) ? Wqs : (gi == 1) ? Wqt : (gi == 2) ? Wks
                         : (gi == 3) ? Wkt : (gi == 4) ? Wvs : Wvt;
        pack_chunk(src, Wp, (gi >> 1) * 1024, (gi & 1) * 1024, idx);
        return;
    }
    for (int n = threadIdx.x; n < NN; n += 256) {   // bias tail
        int g = n >> 10, c = n & 1023;
        const float* a = (g == 0) ? bqs : ((g == 1) ? bks : bvs);
        const float* b = (g == 0) ? bqt : ((g == 1) ? bkt : bvt);
        biasc[n] = a[c] + b[c];
    }
}

// ---------------------------------------------------------------------------
// QKV GEMM — NEW: 256x256 tile, BK=64, 8 waves (2M x 4N), 512 threads,
// 128 KiB LDS double-buffer, 8-phase schedule with counted vmcnt (T3+T4)
// and setprio around MFMA clusters (T5).  Raw s_barrier only — never
// __syncthreads() (it drains vmcnt and kills the pipeline).
//
// Per K-tile (4 phases x 16 MFMA), tile t in buf[t&1], staging tile t+2
// into the SAME buffer late (read-early / stage-late ledger):
//   P1 (mi0-3 x ni0-1): ds_read aF0(8) + bF0(4)
//   P2 (mi0-3 x ni2-3): ds_read bF1(4)            [B fully read]
//   P3 (mi4-7 x ni2-3): ds_read aF1(8) + STAGE B(t+2)  [A fully read]
//   P4 (mi4-7 x ni0-1): STAGE A(t+2); s_waitcnt vmcnt(8); s_barrier
// vmcnt(8) leaves tiles t+2's 8 loads/thread in flight, confirms t+1
// landed; barrier-exit => all waves confirmed.  Never vmcnt(0) in loop.
// ---------------------------------------------------------------------------
#define VM8 asm volatile("s_waitcnt vmcnt(8)" ::: "memory")
#define VM0 asm volatile("s_waitcnt vmcnt(0)" ::: "memory")
#define VMNONE
#define LGKM0 asm volatile("s_waitcnt lgkmcnt(0)" ::: "memory")

// stage one 128x64 packed half-tile (16 KB): 2 glds16/thread
#define STG(gsrc, ldst) do {                                                  \
    glds16((gsrc) + ((size_t)t << 3), (ldst) + (w << 9));                     \
    glds16((gsrc) + (((size_t)t + 512) << 3), (ldst) + ((w + 8) << 9));       \
  } while (0)

#define KSTEP(P, KT, DO_STAGE, VMOP) do {                                     \
    const bf16* aP = &sA[P][aH][0];                                           \
    const bf16* bP = &sB[P][bH][bR << 6];                                     \
    bf16x8 aF0[4][2], aF1[4][2], bF0[2][2], bF1[2][2];                        \
    /* ---- phase 1 ---- */                                                   \
    _Pragma("unroll")                                                         \
    for (int mi = 0; mi < 4; mi++) {                                          \
      aF0[mi][0] = *(const bf16x8*)&aP[((mi*16+l16)<<6) + ((quad^swz)<<3)];   \
      aF0[mi][1] = *(const bf16x8*)&aP[((mi*16+l16)<<6) + (((4+quad)^swz)<<3)];\
    }                                                                         \
    _Pragma("unroll")                                                         \
    for (int ni = 0; ni < 2; ni++) {                                          \
      bF0[ni][0] = *(const bf16x8*)&bP[((ni*16+l16)<<6) + ((quad^swz)<<3)];   \
      bF0[ni][1] = *(const bf16x8*)&bP[((ni*16+l16)<<6) + (((4+quad)^swz)<<3)];\
    }                                                                         \
    __builtin_amdgcn_s_barrier(); LGKM0;                                      \
    __builtin_amdgcn_s_setprio(1);                                            \
    _Pragma("unroll")                                                         \
    for (int mi = 0; mi < 4; mi++)                                            \
      _Pragma("unroll")                                                       \
      for (int ni = 0; ni < 2; ni++) {                                        \
        acc[mi][ni] = __builtin_amdgcn_mfma_f32_16x16x32_bf16(aF0[mi][0], bF0[ni][0], acc[mi][ni], 0,0,0); \
        acc[mi][ni] = __builtin_amdgcn_mfma_f32_16x16x32_bf16(aF0[mi][1], bF0[ni][1], acc[mi][ni], 0,0,0); \
      }                                                                       \
    __builtin_amdgcn_s_setprio(0);                                            \
    __builtin_amdgcn_s_barrier();                                             \
    /* ---- phase 2 ---- */                                                   \
    _Pragma("unroll")                                                         \
    for (int ni = 0; ni < 2; ni++) {                                          \
      bF1[ni][0] = *(const bf16x8*)&bP[(((ni+2)*16+l16)<<6) + ((quad^swz)<<3)]; \
      bF1[ni][1] = *(const bf16x8*)&bP[(((ni+2)*16+l16)<<6) + (((4+quad)^swz)<<3)]; \
    }                                                                         \
    __builtin_amdgcn_s_barrier(); LGKM0;                                      \
    __builtin_amdgcn_s_setprio(1);                                            \
    _Pragma("unroll")                                                         \
    for (int mi = 0; mi < 4; mi++)                                            \
      _Pragma("unroll")                                                       \
      for (int ni = 0; ni < 2; ni++) {                                        \
        acc[mi][ni+2] = __builtin_amdgcn_mfma_f32_16x16x32_bf16(aF0[mi][0], bF1[ni][0], acc[mi][ni+2], 0,0,0); \
        acc[mi][ni+2] = __builtin_amdgcn_mfma_f32_16x16x32_bf16(aF0[mi][1], bF1[ni][1], acc[mi][ni+2], 0,0,0); \
      }                                                                       \
    __builtin_amdgcn_s_setprio(0);                                            \
    __builtin_amdgcn_s_barrier();                                             \
    /* ---- phase 3: + stage B(t+2) ---- */                                   \
    _Pragma("unroll")                                                         \
    for (int mi = 0; mi < 4; mi++) {                                          \
      aF1[mi][0] = *(const bf16x8*)&aP[(((mi+4)*16+l16)<<6) + ((quad^swz)<<3)]; \
      aF1[mi][1] = *(const bf16x8*)&aP[(((mi+4)*16+l16)<<6) + (((4+quad)^swz)<<3)]; \
    }                                                                         \
    if (DO_STAGE) {                                                           \
      STG(Bg0 + ((size_t)((KT) + 2) << 13), &sB[P][0][0]);                    \
      STG(Bg1 + ((size_t)((KT) + 2) << 13), &sB[P][1][0]);                    \
    }                                                                         \
    __builtin_amdgcn_s_barrier(); LGKM0;                                      \
    __builtin_amdgcn_s_setprio(1);                                            \
    _Pragma("unroll")                                                         \
    for (int mi = 0; mi < 4; mi++)                                            \
      _Pragma("unroll")                                                       \
      for (int ni = 0; ni < 2; ni++) {                                        \
        acc[mi+4][ni+2] = __builtin_amdgcn_mfma_f32_16x16x32_bf16(aF1[mi][0], bF1[ni][0], acc[mi+4][ni+2], 0,0,0); \
        acc[mi+4][ni+2] = __builtin_amdgcn_mfma_f32_16x16x32_bf16(aF1[mi][1], bF1[ni][1], acc[mi+4][ni+2], 0,0,0); \
      }                                                                       \
    __builtin_amdgcn_s_setprio(0);                                            \
    __builtin_amdgcn_s_barrier();                                             \
    /* ---- phase 4: + stage A(t+2), counted vmcnt ---- */                    \
    if (DO_STAGE) {                                                           \
      STG(Ag0 + ((size_t)((KT) + 2) << 13), &sA[P][0][0]);                    \
      STG(Ag1 + ((size_t)((KT) + 2) << 13), &sA[P][1][0]);                    \
    }                                                                         \
    __builtin_amdgcn_s_barrier();                                             \
    __builtin_amdgcn_s_setprio(1);                                            \
    _Pragma("unroll")                                                         \
    for (int mi = 0; mi < 4; mi++)                                            \
      _Pragma("unroll")                                                       \
      for (int ni = 0; ni < 2; ni++) {                                        \
        acc[mi+4][ni] = __builtin_amdgcn_mfma_f32_16x16x32_bf16(aF1[mi][0], bF0[ni][0], acc[mi+4][ni], 0,0,0); \
        acc[mi+4][ni] = __builtin_amdgcn_mfma_f32_16x16x32_bf16(aF1[mi][1], bF0[ni][1], acc[mi+4][ni], 0,0,0); \
      }                                                                       \
    __builtin_amdgcn_s_setprio(0);                                            \
    VMOP;                                                                     \
    __builtin_amdgcn_s_barrier();                                             \
    __builtin_amdgcn_sched_barrier(0);                                        \
  } while (0)

__global__ __launch_bounds__(512, 2) void gemm_qkv(
    const bf16* __restrict__ Xp, const bf16* __restrict__ Wp,
    const float* __restrict__ biasc,
    bf16* __restrict__ Qb, bf16* __restrict__ Kb, bf16* __restrict__ Vt) {
    // [buf][half 128-rows][128*64 packed-swizzled]  = 128 KiB total
    __shared__ __align__(16) bf16 sA[2][2][8192];
    __shared__ __align__(16) bf16 sB[2][2][8192];

    const int t = threadIdx.x, lane = t & 63, w = t >> 6;
    const int quad = lane >> 4, l16 = lane & 15, swz = l16 & 7;
    const int wq = w & 3;
    const int wm = (w >> 2) * 128;   // wave M offset in 256-tile
    const int wn = wq * 64;          // wave N offset in 256-tile
    const int aH = w >> 2;           // A half this wave reads
    const int bH = wq >> 1;          // B half this wave reads
    const int bR = (wq & 1) * 64;    // row offset inside B half

    const int bx = blockIdx.x, by = blockIdx.y;
    const bf16* Ag0 = Xp + (((size_t)(bx * 2 + 0) * 32) << 13);
    const bf16* Ag1 = Xp + (((size_t)(bx * 2 + 1) * 32) << 13);
    const bf16* Bg0 = Wp + (((size_t)(by * 2 + 0) * 32) << 13);
    const bf16* Bg1 = Wp + (((size_t)(by * 2 + 1) * 32) << 13);

    f32x4 acc[8][4] = {};

    // prologue: stage tiles 0 (buf0) and 1 (buf1); wait for tile 0 only
    STG(Ag0, &sA[0][0][0]); STG(Ag1, &sA[0][1][0]);
    STG(Bg0, &sB[0][0][0]); STG(Bg1, &sB[0][1][0]);
    STG(Ag0 + 8192, &sA[1][0][0]); STG(Ag1 + 8192, &sA[1][1][0]);
    STG(Bg0 + 8192, &sB[1][0][0]); STG(Bg1 + 8192, &sB[1][1][0]);
    VM8;
    __builtin_amdgcn_s_barrier();
    __builtin_amdgcn_sched_barrier(0);

    int kt = 0;
#pragma unroll 1
    for (int i = 0; i < 15; i++, kt += 2) {   // tiles 0..29, staging 2..31
        KSTEP(0, kt, 1, VM8);
        KSTEP(1, kt + 1, 1, VM8);
    }
    KSTEP(0, 30, 0, VM0);      // drain: only tile 31's loads remain
    KSTEP(1, 31, 0, VMNONE);

    // epilogue (same routing as proven 128x128 kernel, mi now 0..7)
    const int g = by >> 2;
    const int m00 = bx << 8, n00 = by << 8;
#pragma unroll
    for (int mi = 0; mi < 8; mi++) {
        int mbase = m00 + wm + mi * 16 + quad * 4;
#pragma unroll
        for (int ni = 0; ni < 4; ni++) {
            int n = n00 + wn + ni * 16 + l16;
            float bias = biasc[n];
            int c = n & 1023, h = c >> 6, d = c & 63;
#pragma unroll
            for (int r = 0; r < 4; r++) {
                int m = mbase + r;
                int b = m >> 11, s = m & 2047;
                size_t bh = (size_t)(b * NHEAD + h);
                float v = acc[mi][ni][r] + bias;
                if (g == 0)
                    Qb[(bh * SS + s) * DK + d] = (bf16)(v * QSCALE);
                else if (g == 1)
                    Kb[(bh * SS + s) * DK + d] = (bf16)v;
                else
                    Vt[(bh * DK + d) * SS + s] = (bf16)v;
            }
        }
    }
}

// ---------------------------------------------------------------------------
// Flash attention — unchanged (R3 config, XCD-aware swizzle).
// ---------------------------------------------------------------------------
__global__ __launch_bounds__(256) void attn(
    const bf16* __restrict__ Qb, const bf16* __restrict__ Kb,
    const bf16* __restrict__ Vt, float* __restrict__ out) {
    __shared__ __align__(16) bf16 sK[64 * 64];
    __shared__ __align__(16) bf16 sV[64 * 64];
    __shared__ __align__(16) bf16 sP[4][32 * LDP];

    const int lid = blockIdx.x + gridDim.x * blockIdx.y;   // 0..1023
    const int bh = (lid & 7) * 8 + ((lid >> 3) & 7);       // 0..63
    const int q0 = (lid >> 6) * 128;                       // 0..15 tiles

    const int t = threadIdx.x;
    const int lane = t & 63, w = t >> 6;
    const int quad = lane >> 4, l16 = lane & 15, swz = l16 & 7;
    const int b = bh >> 4, h = bh & 15;

    const bf16* Qp = Qb + ((size_t)bh * SS + q0 + w * 32) * DK;
    bf16x8 qf[2][2];
#pragma unroll
    for (int f = 0; f < 2; f++)
#pragma unroll
        for (int kb = 0; kb < 2; kb++)
            qf[f][kb] = *(const bf16x8*)&Qp[(f * 16 + l16) * DK + kb * 32 + quad * 8];

    f32x4 o[2][4] = {};
    float lsum[2] = {0.f, 0.f};

    const bf16* Kp = Kb + (size_t)bh * SS * DK;
    const bf16* Vp = Vt + (size_t)bh * DK * SS;

    for (int kt = 0; kt < SS; kt += 64) {
#pragma unroll
        for (int j = 0; j < 2; j++) {
            int u = (w * 2 + j) * 64 + lane;
            int row = u >> 3;
            int cc = (u & 7) ^ (row & 7);   // global-side swizzle
            glds16(Kp + (size_t)(kt + row) * DK + cc * 8, &sK[(w * 2 + j) * 512]);
            glds16(Vp + (size_t)row * SS + kt + cc * 8, &sV[(w * 2 + j) * 512]);
        }
        __syncthreads();

        // S^T = K * Q^T
        f32x4 st[2][4] = {};
#pragma unroll
        for (int kb = 0; kb < 2; kb++)
#pragma unroll
            for (int ki = 0; ki < 4; ki++) {
                bf16x8 kf = *(const bf16x8*)&sK[(ki * 16 + l16) * 64 + (((kb * 4 + quad) ^ swz) * 8)];
                st[0][ki] = __builtin_amdgcn_mfma_f32_16x16x32_bf16(kf, qf[0][kb], st[0][ki], 0, 0, 0);
                st[1][ki] = __builtin_amdgcn_mfma_f32_16x16x32_bf16(kf, qf[1][kb], st[1][ki], 0, 0, 0);
            }

        // p = exp2(s); deferred denominator
#pragma unroll
        for (int f = 0; f < 2; f++) {
            float ls = 0.f;
#pragma unroll
            for (int ki = 0; ki < 4; ki++) {
                float p0 = __builtin_amdgcn_exp2f(st[f][ki][0]);
                float p1 = __builtin_amdgcn_exp2f(st[f][ki][1]);
                float p2 = __builtin_amdgcn_exp2f(st[f][ki][2]);
                float p3 = __builtin_amdgcn_exp2f(st[f][ki][3]);
                ls += (p0 + p1) + (p2 + p3);
                bf16x4 pk;
                pk[0] = (bf16)p0; pk[1] = (bf16)p1; pk[2] = (bf16)p2; pk[3] = (bf16)p3;
                *(bf16x4*)&sP[w][(f * 16 + l16) * LDP + ki * 16 + quad * 4] = pk;
            }
            lsum[f] += ls;
        }

        // O += P*V
#pragma unroll
        for (int kb = 0; kb < 2; kb++) {
            bf16x8 af0 = *(const bf16x8*)&sP[w][(l16) * LDP + kb * 32 + quad * 8];
            bf16x8 af1 = *(const bf16x8*)&sP[w][(16 + l16) * LDP + kb * 32 + quad * 8];
#pragma unroll
            for (int ni = 0; ni < 4; ni++) {
                bf16x8 vf = *(const bf16x8*)&sV[(ni * 16 + l16) * 64 + (((kb * 4 + quad) ^ swz) * 8)];
                o[0][ni] = __builtin_amdgcn_mfma_f32_16x16x32_bf16(af0, vf, o[0][ni], 0, 0, 0);
                o[1][ni] = __builtin_amdgcn_mfma_f32_16x16x32_bf16(af1, vf, o[1][ni], 0, 0, 0);
            }
        }
        __syncthreads();
    }

#pragma unroll
    for (int f = 0; f < 2; f++) {
        lsum[f] += __shfl_xor(lsum[f], 16);
        lsum[f] += __shfl_xor(lsum[f], 32);
    }

    float* op = out + ((size_t)(b * SS + q0 + w * 32)) * D_MODEL + h * DK;
#pragma unroll
    for (int f = 0; f < 2; f++)
#pragma unroll
        for (int r = 0; r < 4; r++) {
            float linv = 1.0f / __shfl(lsum[f], quad * 4 + r);
#pragma unroll
            for (int ni = 0; ni < 4; ni++)
                op[(f * 16 + quad * 4 + r) * D_MODEL + ni * 16 + l16] = o[f][ni][r] * linv;
        }
}

extern "C" void kernel_launch(void* const* d_in, const int* in_sizes, int n_in,
                              void* d_out, int out_size, void* d_ws, size_t ws_size,
                              hipStream_t stream) {
    const float* Xs   = (const float*)d_in[0];
    const float* Xt   = (const float*)d_in[1];
    const float* Wqs  = (const float*)d_in[2];
    const float* bqs  = (const float*)d_in[3];
    const float* Wqt  = (const float*)d_in[4];
    const float* bqt  = (const float*)d_in[5];
    const float* Wks  = (const float*)d_in[6];
    const float* bks  = (const float*)d_in[7];
    const float* Wkt  = (const float*)d_in[8];
    const float* bkt  = (const float*)d_in[9];
    const float* Wvs  = (const float*)d_in[10];
    const float* bvs  = (const float*)d_in[11];
    const float* Wvt  = (const float*)d_in[12];
    const float* bvt  = (const float*)d_in[13];
    float* out = (float*)d_out;

    char* ws = (char*)d_ws;
    bf16*  Xp    = (bf16*)(ws);                 // 32 MB packed-swizzled
    bf16*  Wp    = (bf16*)(ws + 33554432);      // 12 MB packed-swizzled
    float* biasc = (float*)(ws + 46137344);     // 12 KB
    bf16*  Qb    = (bf16*)(ws + 46149632);      // 16 MB
    bf16*  Kb    = (bf16*)(ws + 62926848);      // 16 MB
    bf16*  Vt    = (bf16*)(ws + 79704064);      // 16 MB

    pack_all<<<11265, 256, 0, stream>>>(Xs, Xt, Wqs, Wqt, Wks, Wkt, Wvs, Wvt,
                                        bqs, bqt, bks, bkt, bvs, bvt,
                                        Xp, Wp, biasc);

    gemm_qkv<<<dim3(MM / 256, NN / 256), 512, 0, stream>>>(Xp, Wp, biasc, Qb, Kb, Vt);

    attn<<<dim3(SS / 128, BB * NHEAD), 256, 0, stream>>>(Qb, Kb, Vt, out);
}

// Round 3
// 370.495 us; speedup vs baseline: 1.0428x; 1.0428x over previous
//
#include <hip/hip_runtime.h>
#include <hip/hip_bf16.h>

typedef __bf16 bf16;
typedef __attribute__((ext_vector_type(8))) __bf16 bf16x8;
typedef __attribute__((ext_vector_type(4))) __bf16 bf16x4;
typedef __attribute__((ext_vector_type(4))) float f32x4;

#define D_MODEL 1024
#define NHEAD 16
#define DK 64
#define BB 4
#define SS 2048
#define MM 8192
#define KK 2048
#define NN 3072

#define LDP 72
#define QSCALE 0.18033688011112042f  // 0.125 * log2(e)

__device__ __forceinline__ void glds16(const bf16* g, bf16* s) {
    __builtin_amdgcn_global_load_lds(
        (const __attribute__((address_space(1))) void*)g,
        (__attribute__((address_space(3))) void*)s, 16, 0, 0);
}

// ---------------------------------------------------------------------------
// Tile-packed XOR-swizzled layout: tile=128 rows x 64 cols, chunk c of row mi
// at slot mi*8 + (c^(mi&7)); tiles [row_tile][k_tile].  (unchanged, proven)
// ---------------------------------------------------------------------------
__device__ __forceinline__ void pack_chunk(const float* __restrict__ src,
                                           bf16* __restrict__ dst,
                                           int row_off, int col_off, int idx) {
    int m = idx >> 7;        // source row (1024 cols = 128 chunks)
    int cl = idx & 127;
    const float4* s4 = (const float4*)&src[((size_t)m << 10) + cl * 8];
    float4 v0 = s4[0], v1 = s4[1];
    bf16x8 o;
    o[0]=(bf16)v0.x; o[1]=(bf16)v0.y; o[2]=(bf16)v0.z; o[3]=(bf16)v0.w;
    o[4]=(bf16)v1.x; o[5]=(bf16)v1.y; o[6]=(bf16)v1.z; o[7]=(bf16)v1.w;
    int r = row_off + m;
    int k = col_off + cl * 8;
    int mi = r & 127, mt = r >> 7;
    int c = (k >> 3) & 7, kt = k >> 6;
    int slot = mi * 8 + (c ^ (mi & 7));
    *(bf16x8*)&dst[(((((size_t)mt * 32 + kt) << 10) + slot) << 3)] = o;
}

// One kernel packs X (2*2^20 chunks), W (6*2^17 chunks), bias (tail block).
__global__ void pack_all(const float* __restrict__ Xs, const float* __restrict__ Xt,
                         const float* __restrict__ Wqs, const float* __restrict__ Wqt,
                         const float* __restrict__ Wks, const float* __restrict__ Wkt,
                         const float* __restrict__ Wvs, const float* __restrict__ Wvt,
                         const float* __restrict__ bqs, const float* __restrict__ bqt,
                         const float* __restrict__ bks, const float* __restrict__ bkt,
                         const float* __restrict__ bvs, const float* __restrict__ bvt,
                         bf16* __restrict__ Xp, bf16* __restrict__ Wp,
                         float* __restrict__ biasc) {
    int blk = blockIdx.x;
    if (blk < 8192) {                      // X: 2 * 1,048,576 chunks
        int i = blk * 256 + threadIdx.x;
        int sel = i >> 20;
        int idx = i & 1048575;
        pack_chunk(sel ? Xt : Xs, Xp, 0, sel ? 1024 : 0, idx);
        return;
    }
    if (blk < 11264) {                     // W: 6 * 131,072 chunks
        int i = (blk - 8192) * 256 + threadIdx.x;
        int gi = i >> 17;
        int idx = i & 131071;
        const float* src = (gi == 0) ? Wqs : (gi == 1) ? Wqt : (gi == 2) ? Wks
                         : (gi == 3) ? Wkt : (gi == 4) ? Wvs : Wvt;
        pack_chunk(src, Wp, (gi >> 1) * 1024, (gi & 1) * 1024, idx);
        return;
    }
    for (int n = threadIdx.x; n < NN; n += 256) {   // bias tail
        int g = n >> 10, c = n & 1023;
        const float* a = (g == 0) ? bqs : ((g == 1) ? bks : bvs);
        const float* b = (g == 0) ? bqt : ((g == 1) ? bkt : bvt);
        biasc[n] = a[c] + b[c];
    }
}

// ---------------------------------------------------------------------------
// QKV GEMM — R2 (resubmit): 128x256 tile, BK=64, 8 waves (2M x 4N) each
// computing 64x64, 96 KiB LDS double-buffer.  TWO barriers per K-tile:
//   [tile start] issue all 16 ds_read_b128 (compiler interleaves with MFMA
//                via its own counted lgkmcnt — proven near-optimal, m97)
//   kb0 MFMA cluster (16)
//   lgkm0; s_barrier              -> all waves' reads of buf[p] retired
//   stage tile t+2 into buf[p] (6 x global_load_lds, counted by vmcnt)
//   kb1 MFMA cluster (16)
//   s_waitcnt vmcnt(6); s_barrier -> tile t+1 landed (t+2's 6 stay in flight)
// Never vmcnt(0) in the main loop (T4).  Grid 64x12 = 768 blocks = 3.0 exact
// occupancy rounds at 1 block/CU (fixes the 1.5-round tail of R1).
// ---------------------------------------------------------------------------
#define VM6 asm volatile("s_waitcnt vmcnt(6)" ::: "memory")
#define VM0 asm volatile("s_waitcnt vmcnt(0)" ::: "memory")
#define VMNONE
#define LGKM0 asm volatile("s_waitcnt lgkmcnt(0)" ::: "memory")

// stage one 128x64 packed tile (16 KB): 2 glds16/thread (512 threads)
#define STG(gsrc, ldst) do {                                                  \
    glds16((gsrc) + ((size_t)t << 3), (ldst) + (w << 9));                     \
    glds16((gsrc) + (((size_t)t + 512) << 3), (ldst) + ((w + 8) << 9));       \
  } while (0)

#define TILE(P, KT, DO_STAGE, VMOP) do {                                      \
    const bf16* aP = &sA[P][wm << 6];                                         \
    const bf16* bP = &sB[P][bH][bR << 6];                                     \
    bf16x8 aF[4][2], bF[4][2];                                                \
    _Pragma("unroll")                                                         \
    for (int mi = 0; mi < 4; mi++)                                            \
      aF[mi][0] = *(const bf16x8*)&aP[((mi*16+l16)<<6) + ((quad^swz)<<3)];    \
    _Pragma("unroll")                                                         \
    for (int ni = 0; ni < 4; ni++)                                            \
      bF[ni][0] = *(const bf16x8*)&bP[((ni*16+l16)<<6) + ((quad^swz)<<3)];    \
    _Pragma("unroll")                                                         \
    for (int mi = 0; mi < 4; mi++)                                            \
      aF[mi][1] = *(const bf16x8*)&aP[((mi*16+l16)<<6) + (((4+quad)^swz)<<3)];\
    _Pragma("unroll")                                                         \
    for (int ni = 0; ni < 4; ni++)                                            \
      bF[ni][1] = *(const bf16x8*)&bP[((ni*16+l16)<<6) + (((4+quad)^swz)<<3)];\
    __builtin_amdgcn_s_setprio(1);                                            \
    _Pragma("unroll")                                                         \
    for (int mi = 0; mi < 4; mi++)                                            \
      _Pragma("unroll")                                                       \
      for (int ni = 0; ni < 4; ni++)                                          \
        acc[mi][ni] = __builtin_amdgcn_mfma_f32_16x16x32_bf16(                \
            aF[mi][0], bF[ni][0], acc[mi][ni], 0, 0, 0);                      \
    __builtin_amdgcn_s_setprio(0);                                            \
    LGKM0;                                                                    \
    __builtin_amdgcn_sched_barrier(0);                                        \
    __builtin_amdgcn_s_barrier();                                             \
    __builtin_amdgcn_sched_barrier(0);                                        \
    if (DO_STAGE) {                                                           \
      STG(Ag  + ((size_t)((KT) + 2) << 13), &sA[P][0]);                       \
      STG(Bg0 + ((size_t)((KT) + 2) << 13), &sB[P][0][0]);                    \
      STG(Bg1 + ((size_t)((KT) + 2) << 13), &sB[P][1][0]);                    \
    }                                                                         \
    __builtin_amdgcn_s_setprio(1);                                            \
    _Pragma("unroll")                                                         \
    for (int mi = 0; mi < 4; mi++)                                            \
      _Pragma("unroll")                                                       \
      for (int ni = 0; ni < 4; ni++)                                          \
        acc[mi][ni] = __builtin_amdgcn_mfma_f32_16x16x32_bf16(                \
            aF[mi][1], bF[ni][1], acc[mi][ni], 0, 0, 0);                      \
    __builtin_amdgcn_s_setprio(0);                                            \
    VMOP;                                                                     \
    __builtin_amdgcn_s_barrier();                                             \
    __builtin_amdgcn_sched_barrier(0);                                        \
  } while (0)

__global__ __launch_bounds__(512, 2) void gemm_qkv(
    const bf16* __restrict__ Xp, const bf16* __restrict__ Wp,
    const float* __restrict__ biasc,
    bf16* __restrict__ Qb, bf16* __restrict__ Kb, bf16* __restrict__ Vt) {
    // A: [buf][128x64 packed]; B: [buf][half 128-rows][128x64 packed] = 96 KiB
    __shared__ __align__(16) bf16 sA[2][8192];
    __shared__ __align__(16) bf16 sB[2][2][8192];

    const int t = threadIdx.x, lane = t & 63, w = t >> 6;
    const int quad = lane >> 4, l16 = lane & 15, swz = l16 & 7;
    const int wq = w & 3;
    const int wm = (w >> 2) * 64;    // wave M offset in 128-tile
    const int wn = wq * 64;          // wave N offset in 256-tile
    const int bH = wq >> 1;          // B half this wave reads
    const int bR = (wq & 1) * 64;    // row offset inside B half

    const int bx = blockIdx.x, by = blockIdx.y;
    const bf16* Ag  = Xp + (((size_t)bx * 32) << 13);
    const bf16* Bg0 = Wp + (((size_t)(by * 2 + 0) * 32) << 13);
    const bf16* Bg1 = Wp + (((size_t)(by * 2 + 1) * 32) << 13);

    f32x4 acc[4][4] = {};

    // prologue: stage tiles 0 (buf0) and 1 (buf1); wait for tile 0 only
    STG(Ag, &sA[0][0]); STG(Bg0, &sB[0][0][0]); STG(Bg1, &sB[0][1][0]);
    STG(Ag + 8192, &sA[1][0]); STG(Bg0 + 8192, &sB[1][0][0]); STG(Bg1 + 8192, &sB[1][1][0]);
    VM6;
    __builtin_amdgcn_s_barrier();
    __builtin_amdgcn_sched_barrier(0);

    int kt = 0;
#pragma unroll 1
    for (int i = 0; i < 15; i++, kt += 2) {   // tiles 0..29, staging 2..31
        TILE(0, kt, 1, VM6);
        TILE(1, kt + 1, 1, VM6);
    }
    TILE(0, 30, 0, VM0);      // drain: only tile 31's loads remain
    TILE(1, 31, 0, VMNONE);

    // epilogue (proven routing; BM=128 so m00 = bx<<7)
    const int g = by >> 2;
    const int m00 = bx << 7, n00 = by << 8;
#pragma unroll
    for (int mi = 0; mi < 4; mi++) {
        int mbase = m00 + wm + mi * 16 + quad * 4;
#pragma unroll
        for (int ni = 0; ni < 4; ni++) {
            int n = n00 + wn + ni * 16 + l16;
            float bias = biasc[n];
            int c = n & 1023, h = c >> 6, d = c & 63;
#pragma unroll
            for (int r = 0; r < 4; r++) {
                int m = mbase + r;
                int b = m >> 11, s = m & 2047;
                size_t bh = (size_t)(b * NHEAD + h);
                float v = acc[mi][ni][r] + bias;
                if (g == 0)
                    Qb[(bh * SS + s) * DK + d] = (bf16)(v * QSCALE);
                else if (g == 1)
                    Kb[(bh * SS + s) * DK + d] = (bf16)v;
                else
                    Vt[(bh * DK + d) * SS + s] = (bf16)v;
            }
        }
    }
}

// ---------------------------------------------------------------------------
// Flash attention — unchanged (R0 config, proven).
// ---------------------------------------------------------------------------
__global__ __launch_bounds__(256) void attn(
    const bf16* __restrict__ Qb, const bf16* __restrict__ Kb,
    const bf16* __restrict__ Vt, float* __restrict__ out) {
    __shared__ __align__(16) bf16 sK[64 * 64];
    __shared__ __align__(16) bf16 sV[64 * 64];
    __shared__ __align__(16) bf16 sP[4][32 * LDP];

    const int lid = blockIdx.x + gridDim.x * blockIdx.y;   // 0..1023
    const int bh = (lid & 7) * 8 + ((lid >> 3) & 7);       // 0..63
    const int q0 = (lid >> 6) * 128;                       // 0..15 tiles

    const int t = threadIdx.x;
    const int lane = t & 63, w = t >> 6;
    const int quad = lane >> 4, l16 = lane & 15, swz = l16 & 7;
    const int b = bh >> 4, h = bh & 15;

    const bf16* Qp = Qb + ((size_t)bh * SS + q0 + w * 32) * DK;
    bf16x8 qf[2][2];
#pragma unroll
    for (int f = 0; f < 2; f++)
#pragma unroll
        for (int kb = 0; kb < 2; kb++)
            qf[f][kb] = *(const bf16x8*)&Qp[(f * 16 + l16) * DK + kb * 32 + quad * 8];

    f32x4 o[2][4] = {};
    float lsum[2] = {0.f, 0.f};

    const bf16* Kp = Kb + (size_t)bh * SS * DK;
    const bf16* Vp = Vt + (size_t)bh * DK * SS;

    for (int kt = 0; kt < SS; kt += 64) {
#pragma unroll
        for (int j = 0; j < 2; j++) {
            int u = (w * 2 + j) * 64 + lane;
            int row = u >> 3;
            int cc = (u & 7) ^ (row & 7);   // global-side swizzle
            glds16(Kp + (size_t)(kt + row) * DK + cc * 8, &sK[(w * 2 + j) * 512]);
            glds16(Vp + (size_t)row * SS + kt + cc * 8, &sV[(w * 2 + j) * 512]);
        }
        __syncthreads();

        // S^T = K * Q^T
        f32x4 st[2][4] = {};
#pragma unroll
        for (int kb = 0; kb < 2; kb++)
#pragma unroll
            for (int ki = 0; ki < 4; ki++) {
                bf16x8 kf = *(const bf16x8*)&sK[(ki * 16 + l16) * 64 + (((kb * 4 + quad) ^ swz) * 8)];
                st[0][ki] = __builtin_amdgcn_mfma_f32_16x16x32_bf16(kf, qf[0][kb], st[0][ki], 0, 0, 0);
                st[1][ki] = __builtin_amdgcn_mfma_f32_16x16x32_bf16(kf, qf[1][kb], st[1][ki], 0, 0, 0);
            }

        // p = exp2(s); deferred denominator
#pragma unroll
        for (int f = 0; f < 2; f++) {
            float ls = 0.f;
#pragma unroll
            for (int ki = 0; ki < 4; ki++) {
                float p0 = __builtin_amdgcn_exp2f(st[f][ki][0]);
                float p1 = __builtin_amdgcn_exp2f(st[f][ki][1]);
                float p2 = __builtin_amdgcn_exp2f(st[f][ki][2]);
                float p3 = __builtin_amdgcn_exp2f(st[f][ki][3]);
                ls += (p0 + p1) + (p2 + p3);
                bf16x4 pk;
                pk[0] = (bf16)p0; pk[1] = (bf16)p1; pk[2] = (bf16)p2; pk[3] = (bf16)p3;
                *(bf16x4*)&sP[w][(f * 16 + l16) * LDP + ki * 16 + quad * 4] = pk;
            }
            lsum[f] += ls;
        }

        // O += P*V
#pragma unroll
        for (int kb = 0; kb < 2; kb++) {
            bf16x8 af0 = *(const bf16x8*)&sP[w][(l16) * LDP + kb * 32 + quad * 8];
            bf16x8 af1 = *(const bf16x8*)&sP[w][(16 + l16) * LDP + kb * 32 + quad * 8];
#pragma unroll
            for (int ni = 0; ni < 4; ni++) {
                bf16x8 vf = *(const bf16x8*)&sV[(ni * 16 + l16) * 64 + (((kb * 4 + quad) ^ swz) * 8)];
                o[0][ni] = __builtin_amdgcn_mfma_f32_16x16x32_bf16(af0, vf, o[0][ni], 0, 0, 0);
                o[1][ni] = __builtin_amdgcn_mfma_f32_16x16x32_bf16(af1, vf, o[1][ni], 0, 0, 0);
            }
        }
        __syncthreads();
    }

#pragma unroll
    for (int f = 0; f < 2; f++) {
        lsum[f] += __shfl_xor(lsum[f], 16);
        lsum[f] += __shfl_xor(lsum[f], 32);
    }

    float* op = out + ((size_t)(b * SS + q0 + w * 32)) * D_MODEL + h * DK;
#pragma unroll
    for (int f = 0; f < 2; f++)
#pragma unroll
        for (int r = 0; r < 4; r++) {
            float linv = 1.0f / __shfl(lsum[f], quad * 4 + r);
#pragma unroll
            for (int ni = 0; ni < 4; ni++)
                op[(f * 16 + quad * 4 + r) * D_MODEL + ni * 16 + l16] = o[f][ni][r] * linv;
        }
}

extern "C" void kernel_launch(void* const* d_in, const int* in_sizes, int n_in,
                              void* d_out, int out_size, void* d_ws, size_t ws_size,
                              hipStream_t stream) {
    const float* Xs   = (const float*)d_in[0];
    const float* Xt   = (const float*)d_in[1];
    const float* Wqs  = (const float*)d_in[2];
    const float* bqs  = (const float*)d_in[3];
    const float* Wqt  = (const float*)d_in[4];
    const float* bqt  = (const float*)d_in[5];
    const float* Wks  = (const float*)d_in[6];
    const float* bks  = (const float*)d_in[7];
    const float* Wkt  = (const float*)d_in[8];
    const float* bkt  = (const float*)d_in[9];
    const float* Wvs  = (const float*)d_in[10];
    const float* bvs  = (const float*)d_in[11];
    const float* Wvt  = (const float*)d_in[12];
    const float* bvt  = (const float*)d_in[13];
    float* out = (float*)d_out;

    char* ws = (char*)d_ws;
    bf16*  Xp    = (bf16*)(ws);                 // 32 MB packed-swizzled
    bf16*  Wp    = (bf16*)(ws + 33554432);      // 12 MB packed-swizzled
    float* biasc = (float*)(ws + 46137344);     // 12 KB
    bf16*  Qb    = (bf16*)(ws + 46149632);      // 16 MB
    bf16*  Kb    = (bf16*)(ws + 62926848);      // 16 MB
    bf16*  Vt    = (bf16*)(ws + 79704064);      // 16 MB

    pack_all<<<11265, 256, 0, stream>>>(Xs, Xt, Wqs, Wqt, Wks, Wkt, Wvs, Wvt,
                                        bqs, bqt, bks, bkt, bvs, bvt,
                                        Xp, Wp, biasc);

    gemm_qkv<<<dim3(MM / 128, NN / 256), 512, 0, stream>>>(Xp, Wp, biasc, Qb, Kb, Vt);

    attn<<<dim3(SS / 128, BB * NHEAD), 256, 0, stream>>>(Qb, Kb, Vt, out);
}

// Round 4
// 366.017 us; speedup vs baseline: 1.0555x; 1.0122x over previous
//
#include <hip/hip_runtime.h>
#include <hip/hip_bf16.h>

typedef __bf16 bf16;
typedef __attribute__((ext_vector_type(8))) __bf16 bf16x8;
typedef __attribute__((ext_vector_type(4))) __bf16 bf16x4;
typedef __attribute__((ext_vector_type(4))) float f32x4;

#define D_MODEL 1024
#define NHEAD 16
#define DK 64
#define BB 4
#define SS 2048
#define MM 8192
#define KK 2048
#define NN 3072

#define LDP 72
#define QSCALE 0.18033688011112042f  // 0.125 * log2(e)

__device__ __forceinline__ void glds16(const bf16* g, bf16* s) {
    __builtin_amdgcn_global_load_lds(
        (const __attribute__((address_space(1))) void*)g,
        (__attribute__((address_space(3))) void*)s, 16, 0, 0);
}

// ---------------------------------------------------------------------------
// Tile-packed XOR-swizzled layout: tile=128 rows x 64 cols, chunk c of row mi
// at slot mi*8 + (c^(mi&7)); tiles [row_tile][k_tile].  (unchanged, proven)
// ---------------------------------------------------------------------------
__device__ __forceinline__ void pack_chunk(const float* __restrict__ src,
                                           bf16* __restrict__ dst,
                                           int row_off, int col_off, int idx) {
    int m = idx >> 7;        // source row (1024 cols = 128 chunks)
    int cl = idx & 127;
    const float4* s4 = (const float4*)&src[((size_t)m << 10) + cl * 8];
    float4 v0 = s4[0], v1 = s4[1];
    bf16x8 o;
    o[0]=(bf16)v0.x; o[1]=(bf16)v0.y; o[2]=(bf16)v0.z; o[3]=(bf16)v0.w;
    o[4]=(bf16)v1.x; o[5]=(bf16)v1.y; o[6]=(bf16)v1.z; o[7]=(bf16)v1.w;
    int r = row_off + m;
    int k = col_off + cl * 8;
    int mi = r & 127, mt = r >> 7;
    int c = (k >> 3) & 7, kt = k >> 6;
    int slot = mi * 8 + (c ^ (mi & 7));
    *(bf16x8*)&dst[(((((size_t)mt * 32 + kt) << 10) + slot) << 3)] = o;
}

// One kernel packs X (2*2^20 chunks), W (6*2^17 chunks), bias (tail block).
__global__ void pack_all(const float* __restrict__ Xs, const float* __restrict__ Xt,
                         const float* __restrict__ Wqs, const float* __restrict__ Wqt,
                         const float* __restrict__ Wks, const float* __restrict__ Wkt,
                         const float* __restrict__ Wvs, const float* __restrict__ Wvt,
                         const float* __restrict__ bqs, const float* __restrict__ bqt,
                         const float* __restrict__ bks, const float* __restrict__ bkt,
                         const float* __restrict__ bvs, const float* __restrict__ bvt,
                         bf16* __restrict__ Xp, bf16* __restrict__ Wp,
                         float* __restrict__ biasc) {
    int blk = blockIdx.x;
    if (blk < 8192) {                      // X: 2 * 1,048,576 chunks
        int i = blk * 256 + threadIdx.x;
        int sel = i >> 20;
        int idx = i & 1048575;
        pack_chunk(sel ? Xt : Xs, Xp, 0, sel ? 1024 : 0, idx);
        return;
    }
    if (blk < 11264) {                     // W: 6 * 131,072 chunks
        int i = (blk - 8192) * 256 + threadIdx.x;
        int gi = i >> 17;
        int idx = i & 131071;
        const float* src = (gi == 0) ? Wqs : (gi == 1) ? Wqt : (gi == 2) ? Wks
                         : (gi == 3) ? Wkt : (gi == 4) ? Wvs : Wvt;
        pack_chunk(src, Wp, (gi >> 1) * 1024, (gi & 1) * 1024, idx);
        return;
    }
    for (int n = threadIdx.x; n < NN; n += 256) {   // bias tail
        int g = n >> 10, c = n & 1023;
        const float* a = (g == 0) ? bqs : ((g == 1) ? bks : bvs);
        const float* b = (g == 0) ? bqt : ((g == 1) ? bkt : bvt);
        biasc[n] = a[c] + b[c];
    }
}

// ---------------------------------------------------------------------------
// QKV GEMM — R4: 128x256 tile, BK=64, 8 waves (64x64 each), 96 KiB LDS
// double-buffer, grid 64x12 = 768 = 3.0 exact rounds.  NEW: one-tile
// register-fragment pipeline so the MFMA cluster overlaps BOTH the LDS pipe
// (next tile's ds_reads) and vmem (stage flight).  ONE barrier per tile.
//
// tile t (buf p=t&1):  [frags(t) in regs; buf[p^1]=t+1 confirmed; buf[p] free]
//   stage(t+2)->buf[p]; issue 16 ds_reads frags(t+1)<-buf[p^1];
//   32 MFMA on frags(t);            (hides LDS reads + HBM flight)
//   lgkm0 (frags t+1 ready); vmcnt0 (stage t+2 landed, ~free); s_barrier
// Race ledger: buf[p] free because frags(t) reads (issued at t-1) retired at
// t-1's lgkm0 + barrier; reads of buf[p^1] valid because stage(t+1) was
// vm-waited + barriered at t-1.  sched_barrier(0) fences per rule #18.
// ---------------------------------------------------------------------------
#define VM6 asm volatile("s_waitcnt vmcnt(6)" ::: "memory")
#define VM0 asm volatile("s_waitcnt vmcnt(0)" ::: "memory")
#define VMNONE
#define LGKM0 asm volatile("s_waitcnt lgkmcnt(0)" ::: "memory")

// stage one 128x64 packed tile (16 KB): 2 glds16/thread (512 threads)
#define STG(gsrc, ldst) do {                                                  \
    glds16((gsrc) + ((size_t)t << 3), (ldst) + (w << 9));                     \
    glds16((gsrc) + (((size_t)t + 512) << 3), (ldst) + ((w + 8) << 9));       \
  } while (0)

// read this wave's 16 b128 fragments of tile held in buf Q into AO/BO
#define RD16(Q, AO, BO) do {                                                  \
    const bf16* aP = &sA[Q][wm << 6];                                         \
    const bf16* bP = &sB[Q][bH][bR << 6];                                     \
    _Pragma("unroll")                                                         \
    for (int mi = 0; mi < 4; mi++) {                                          \
      AO[mi][0] = *(const bf16x8*)&aP[((mi*16+l16)<<6) + ((quad^swz)<<3)];    \
      AO[mi][1] = *(const bf16x8*)&aP[((mi*16+l16)<<6) + (((4+quad)^swz)<<3)];\
    }                                                                         \
    _Pragma("unroll")                                                         \
    for (int ni = 0; ni < 4; ni++) {                                          \
      BO[ni][0] = *(const bf16x8*)&bP[((ni*16+l16)<<6) + ((quad^swz)<<3)];    \
      BO[ni][1] = *(const bf16x8*)&bP[((ni*16+l16)<<6) + (((4+quad)^swz)<<3)];\
    }                                                                         \
  } while (0)

#define MM32(AI, BI) do {                                                     \
    __builtin_amdgcn_s_setprio(1);                                            \
    _Pragma("unroll")                                                         \
    for (int kb = 0; kb < 2; kb++)                                            \
      _Pragma("unroll")                                                       \
      for (int mi = 0; mi < 4; mi++)                                          \
        _Pragma("unroll")                                                     \
        for (int ni = 0; ni < 4; ni++)                                        \
          acc[mi][ni] = __builtin_amdgcn_mfma_f32_16x16x32_bf16(              \
              AI[mi][kb], BI[ni][kb], acc[mi][ni], 0, 0, 0);                  \
    __builtin_amdgcn_s_setprio(0);                                            \
  } while (0)

#define TILE(P, KT, AI, BI, AO, BO, DO_STAGE, VMOP) do {                      \
    if (DO_STAGE) {                                                           \
      STG(Ag  + ((size_t)((KT) + 2) << 13), &sA[P][0]);                       \
      STG(Bg0 + ((size_t)((KT) + 2) << 13), &sB[P][0][0]);                    \
      STG(Bg1 + ((size_t)((KT) + 2) << 13), &sB[P][1][0]);                    \
    }                                                                         \
    RD16(P ^ 1, AO, BO);                                                      \
    __builtin_amdgcn_sched_barrier(0);                                        \
    MM32(AI, BI);                                                             \
    __builtin_amdgcn_sched_barrier(0);                                        \
    LGKM0;                                                                    \
    VMOP;                                                                     \
    __builtin_amdgcn_s_barrier();                                             \
    __builtin_amdgcn_sched_barrier(0);                                        \
  } while (0)

__global__ __launch_bounds__(512, 2) void gemm_qkv(
    const bf16* __restrict__ Xp, const bf16* __restrict__ Wp,
    const float* __restrict__ biasc,
    bf16* __restrict__ Qb, bf16* __restrict__ Kb, bf16* __restrict__ Vt) {
    // A: [buf][128x64 packed]; B: [buf][half 128-rows][128x64 packed] = 96 KiB
    __shared__ __align__(16) bf16 sA[2][8192];
    __shared__ __align__(16) bf16 sB[2][2][8192];

    const int t = threadIdx.x, lane = t & 63, w = t >> 6;
    const int quad = lane >> 4, l16 = lane & 15, swz = l16 & 7;
    const int wq = w & 3;
    const int wm = (w >> 2) * 64;    // wave M offset in 128-tile
    const int wn = wq * 64;          // wave N offset in 256-tile
    const int bH = wq >> 1;          // B half this wave reads
    const int bR = (wq & 1) * 64;    // row offset inside B half

    const int bx = blockIdx.x, by = blockIdx.y;
    const bf16* Ag  = Xp + (((size_t)bx * 32) << 13);
    const bf16* Bg0 = Wp + (((size_t)(by * 2 + 0) * 32) << 13);
    const bf16* Bg1 = Wp + (((size_t)(by * 2 + 1) * 32) << 13);

    f32x4 acc[4][4] = {};
    bf16x8 aX[4][2], bX[4][2], aY[4][2], bY[4][2];

    // prologue: stage tiles 0,1; get frags(0) into X; confirm tile 1 landed
    STG(Ag, &sA[0][0]); STG(Bg0, &sB[0][0][0]); STG(Bg1, &sB[0][1][0]);
    STG(Ag + 8192, &sA[1][0]); STG(Bg0 + 8192, &sB[1][0][0]); STG(Bg1 + 8192, &sB[1][1][0]);
    VM6;                                  // tile 0's 6 loads landed (per-wave)
    __builtin_amdgcn_s_barrier();         // all waves: tile 0 in LDS
    __builtin_amdgcn_sched_barrier(0);
    RD16(0, aX, bX);                      // frags(0) <- buf0
    LGKM0;                                // retired (buf0 free for stage(2))
    VM0;                                  // tile 1 landed (per-wave)
    __builtin_amdgcn_s_barrier();         // all waves agree
    __builtin_amdgcn_sched_barrier(0);

    int kt = 0;
#pragma unroll 1
    for (int i = 0; i < 15; i++, kt += 2) {   // tiles 0..29, staging 2..31
        TILE(0, kt,     aX, bX, aY, bY, 1, VM0);
        TILE(1, kt + 1, aY, bY, aX, bX, 1, VM0);
    }
    TILE(0, 30, aX, bX, aY, bY, 0, VMNONE);   // reads frags(31), no stage
    MM32(aY, bY);                              // tile 31

    // epilogue (proven routing; BM=128 so m00 = bx<<7)
    const int g = by >> 2;
    const int m00 = bx << 7, n00 = by << 8;
#pragma unroll
    for (int mi = 0; mi < 4; mi++) {
        int mbase = m00 + wm + mi * 16 + quad * 4;
#pragma unroll
        for (int ni = 0; ni < 4; ni++) {
            int n = n00 + wn + ni * 16 + l16;
            float bias = biasc[n];
            int c = n & 1023, h = c >> 6, d = c & 63;
#pragma unroll
            for (int r = 0; r < 4; r++) {
                int m = mbase + r;
                int b = m >> 11, s = m & 2047;
                size_t bh = (size_t)(b * NHEAD + h);
                float v = acc[mi][ni][r] + bias;
                if (g == 0)
                    Qb[(bh * SS + s) * DK + d] = (bf16)(v * QSCALE);
                else if (g == 1)
                    Kb[(bh * SS + s) * DK + d] = (bf16)v;
                else
                    Vt[(bh * DK + d) * SS + s] = (bf16)v;
            }
        }
    }
}

// ---------------------------------------------------------------------------
// Flash attention — unchanged (R0 config, proven).
// ---------------------------------------------------------------------------
__global__ __launch_bounds__(256) void attn(
    const bf16* __restrict__ Qb, const bf16* __restrict__ Kb,
    const bf16* __restrict__ Vt, float* __restrict__ out) {
    __shared__ __align__(16) bf16 sK[64 * 64];
    __shared__ __align__(16) bf16 sV[64 * 64];
    __shared__ __align__(16) bf16 sP[4][32 * LDP];

    const int lid = blockIdx.x + gridDim.x * blockIdx.y;   // 0..1023
    const int bh = (lid & 7) * 8 + ((lid >> 3) & 7);       // 0..63
    const int q0 = (lid >> 6) * 128;                       // 0..15 tiles

    const int t = threadIdx.x;
    const int lane = t & 63, w = t >> 6;
    const int quad = lane >> 4, l16 = lane & 15, swz = l16 & 7;
    const int b = bh >> 4, h = bh & 15;

    const bf16* Qp = Qb + ((size_t)bh * SS + q0 + w * 32) * DK;
    bf16x8 qf[2][2];
#pragma unroll
    for (int f = 0; f < 2; f++)
#pragma unroll
        for (int kb = 0; kb < 2; kb++)
            qf[f][kb] = *(const bf16x8*)&Qp[(f * 16 + l16) * DK + kb * 32 + quad * 8];

    f32x4 o[2][4] = {};
    float lsum[2] = {0.f, 0.f};

    const bf16* Kp = Kb + (size_t)bh * SS * DK;
    const bf16* Vp = Vt + (size_t)bh * DK * SS;

    for (int kt = 0; kt < SS; kt += 64) {
#pragma unroll
        for (int j = 0; j < 2; j++) {
            int u = (w * 2 + j) * 64 + lane;
            int row = u >> 3;
            int cc = (u & 7) ^ (row & 7);   // global-side swizzle
            glds16(Kp + (size_t)(kt + row) * DK + cc * 8, &sK[(w * 2 + j) * 512]);
            glds16(Vp + (size_t)row * SS + kt + cc * 8, &sV[(w * 2 + j) * 512]);
        }
        __syncthreads();

        // S^T = K * Q^T
        f32x4 st[2][4] = {};
#pragma unroll
        for (int kb = 0; kb < 2; kb++)
#pragma unroll
            for (int ki = 0; ki < 4; ki++) {
                bf16x8 kf = *(const bf16x8*)&sK[(ki * 16 + l16) * 64 + (((kb * 4 + quad) ^ swz) * 8)];
                st[0][ki] = __builtin_amdgcn_mfma_f32_16x16x32_bf16(kf, qf[0][kb], st[0][ki], 0, 0, 0);
                st[1][ki] = __builtin_amdgcn_mfma_f32_16x16x32_bf16(kf, qf[1][kb], st[1][ki], 0, 0, 0);
            }

        // p = exp2(s); deferred denominator
#pragma unroll
        for (int f = 0; f < 2; f++) {
            float ls = 0.f;
#pragma unroll
            for (int ki = 0; ki < 4; ki++) {
                float p0 = __builtin_amdgcn_exp2f(st[f][ki][0]);
                float p1 = __builtin_amdgcn_exp2f(st[f][ki][1]);
                float p2 = __builtin_amdgcn_exp2f(st[f][ki][2]);
                float p3 = __builtin_amdgcn_exp2f(st[f][ki][3]);
                ls += (p0 + p1) + (p2 + p3);
                bf16x4 pk;
                pk[0] = (bf16)p0; pk[1] = (bf16)p1; pk[2] = (bf16)p2; pk[3] = (bf16)p3;
                *(bf16x4*)&sP[w][(f * 16 + l16) * LDP + ki * 16 + quad * 4] = pk;
            }
            lsum[f] += ls;
        }

        // O += P*V
#pragma unroll
        for (int kb = 0; kb < 2; kb++) {
            bf16x8 af0 = *(const bf16x8*)&sP[w][(l16) * LDP + kb * 32 + quad * 8];
            bf16x8 af1 = *(const bf16x8*)&sP[w][(16 + l16) * LDP + kb * 32 + quad * 8];
#pragma unroll
            for (int ni = 0; ni < 4; ni++) {
                bf16x8 vf = *(const bf16x8*)&sV[(ni * 16 + l16) * 64 + (((kb * 4 + quad) ^ swz) * 8)];
                o[0][ni] = __builtin_amdgcn_mfma_f32_16x16x32_bf16(af0, vf, o[0][ni], 0, 0, 0);
                o[1][ni] = __builtin_amdgcn_mfma_f32_16x16x32_bf16(af1, vf, o[1][ni], 0, 0, 0);
            }
        }
        __syncthreads();
    }

#pragma unroll
    for (int f = 0; f < 2; f++) {
        lsum[f] += __shfl_xor(lsum[f], 16);
        lsum[f] += __shfl_xor(lsum[f], 32);
    }

    float* op = out + ((size_t)(b * SS + q0 + w * 32)) * D_MODEL + h * DK;
#pragma unroll
    for (int f = 0; f < 2; f++)
#pragma unroll
        for (int r = 0; r < 4; r++) {
            float linv = 1.0f / __shfl(lsum[f], quad * 4 + r);
#pragma unroll
            for (int ni = 0; ni < 4; ni++)
                op[(f * 16 + quad * 4 + r) * D_MODEL + ni * 16 + l16] = o[f][ni][r] * linv;
        }
}

extern "C" void kernel_launch(void* const* d_in, const int* in_sizes, int n_in,
                              void* d_out, int out_size, void* d_ws, size_t ws_size,
                              hipStream_t stream) {
    const float* Xs   = (const float*)d_in[0];
    const float* Xt   = (const float*)d_in[1];
    const float* Wqs  = (const float*)d_in[2];
    const float* bqs  = (const float*)d_in[3];
    const float* Wqt  = (const float*)d_in[4];
    const float* bqt  = (const float*)d_in[5];
    const float* Wks  = (const float*)d_in[6];
    const float* bks  = (const float*)d_in[7];
    const float* Wkt  = (const float*)d_in[8];
    const float* bkt  = (const float*)d_in[9];
    const float* Wvs  = (const float*)d_in[10];
    const float* bvs  = (const float*)d_in[11];
    const float* Wvt  = (const float*)d_in[12];
    const float* bvt  = (const float*)d_in[13];
    float* out = (float*)d_out;

    char* ws = (char*)d_ws;
    bf16*  Xp    = (bf16*)(ws);                 // 32 MB packed-swizzled
    bf16*  Wp    = (bf16*)(ws + 33554432);      // 12 MB packed-swizzled
    float* biasc = (float*)(ws + 46137344);     // 12 KB
    bf16*  Qb    = (bf16*)(ws + 46149632);      // 16 MB
    bf16*  Kb    = (bf16*)(ws + 62926848);      // 16 MB
    bf16*  Vt    = (bf16*)(ws + 79704064);      // 16 MB

    pack_all<<<11265, 256, 0, stream>>>(Xs, Xt, Wqs, Wqt, Wks, Wkt, Wvs, Wvt,
                                        bqs, bqt, bks, bkt, bvs, bvt,
                                        Xp, Wp, biasc);

    gemm_qkv<<<dim3(MM / 128, NN / 256), 512, 0, stream>>>(Xp, Wp, biasc, Qb, Kb, Vt);

    attn<<<dim3(SS / 128, BB * NHEAD), 256, 0, stream>>>(Qb, Kb, Vt, out);
}